// Round 17
// baseline (125.849 us; speedup 1.0000x reference)
//
#include <hip/hip_runtime.h>
#include <hip/hip_bf16.h>
#include <cstddef>

#define N_ROWS 8192
#define M_ROWS 8192
#define D_IN   64
#define H_DIM  32
#define T_OUT  8

#define NSPLIT   32          // j-splits (blockIdx.y); grid 32x32 = 1024 blocks
#define JSLICE   (M_ROWS / NSPLIT)   // 256 cols per block
#define JTILE    32
#define NTILES   (JSLICE / JTILE)    // 8 j-tiles per block
#define NSTAGES  (NTILES / 2)        // 4 two-tile stages
#define LOG2E    1.4426950408889634f
#define NHALF_SC (-0.72134752044448169f)   // -0.5*log2(e)

// Stage buffer (2 j-tiles): KH_A 2048 | KL_A 2048 | KH_B 2048 | KL_B 2048 |
// YI_A 4096 | YI_B 4096 | CK 256  = 16640 B; double-buffered = 33280 B.
#define YI_OFF  8192
#define CK_OFF  16384
#define STAGEBUF 16640

typedef _Float16 half8  __attribute__((ext_vector_type(8)));
typedef _Float16 half4v __attribute__((ext_vector_type(4)));
typedef __fp16   fp16x2 __attribute__((ext_vector_type(2)));
typedef float    f32x16 __attribute__((ext_vector_type(16)));

__device__ __forceinline__ half8 ld_h8(const _Float16* p) {
    return *(const half8*)p;
}

// ---------------------------------------------------------------------------
// Feature storage: FRAGMENT-ORDER, K=32 (2 chunks of 16; norms applied in
// the pair epilogue as exact f32). For 32-row tile T, chunk c, lane
// l = h*32+n holds feat[T*32+n][16c+8h..+8) at ((T*2 + c)*64 + l)*8 halves.
// ---------------------------------------------------------------------------

// ---------------------------------------------------------------------------
// Kernel 1 (fused prep): blocks 0..511 = features (column-split MLP) + ns;
// blocks 512..767 = Y_target PV B-fragments (hi|lo interleaved).
// ---------------------------------------------------------------------------
__global__ __launch_bounds__(256) void prep_kernel(
    const float* __restrict__ X, const float* __restrict__ Y,
    const float* __restrict__ Yt,
    const float* __restrict__ W1, const float* __restrict__ b1,
    const float* __restrict__ W2, const float* __restrict__ b2,
    const float* __restrict__ W3, const float* __restrict__ b3,
    _Float16* __restrict__ fh, _Float16* __restrict__ fl,
    _Float16* __restrict__ yfi, float* __restrict__ ns)
{
    __shared__ float xs [32 * 65];
    __shared__ float w1l[64 * 36];
    __shared__ float w2l[32 * 36];
    __shared__ float w3l[32 * 36];
    __shared__ float h1t[32 * 33];
    __shared__ float h2t[32 * 33];
    __shared__ float psums[8 * 32];
    __shared__ float bl[96];

    const int tid = threadIdx.x;

    if (blockIdx.x >= 512) {
        // Ytt[j][t] = Yt[j][t] (t<8), 1 (t==8), 0 (t>8); hi|lo interleaved.
        const int idx = (blockIdx.x - 512) * 256 + tid;   // 0..65535
        const int lane = idx & 63;
        const int jtg  = idx >> 6;
        const int g    = jtg & 3;
        const int jt   = jtg >> 2;
        const int t    = lane & 31;
        const int h    = lane >> 5;
        const int j    = jt * 32 + g * 8 + h * 4;
        union { _Float16 hh[8]; uint4 u; } V;
        #pragma unroll
        for (int i = 0; i < 4; ++i) {
            float v = (t < T_OUT) ? Yt[(size_t)(j + i) * T_OUT + t]
                                  : (t == 8 ? 1.0f : 0.0f);
            _Float16 hi = (_Float16)v;     // RNE
            V.hh[i]     = hi;
            V.hh[4 + i] = (_Float16)(v - (float)hi);
        }
        *(uint4*)(yfi + (size_t)idx * 8) = V.u;
        return;
    }

    // ---- feat: rows 0..N-1 = MLP(X)*log2e; rows N.. = MLP(Y) unscaled. ----
    const int rowbase = blockIdx.x * 32;
    const bool isX = rowbase < N_ROWS;
    const float* src = isX ? (X + (size_t)rowbase * D_IN)
                           : (Y + (size_t)(rowbase - N_ROWS) * D_IN);

    {
        const float4* g4 = (const float4*)src;
        int i0 = tid * 2;
        float4 v0 = g4[i0], v1 = g4[i0 + 1];
        int f0 = tid * 8;
        int r = f0 >> 6, c = f0 & 63;
        float* dst = xs + r * 65 + c;
        dst[0] = v0.x; dst[1] = v0.y; dst[2] = v0.z; dst[3] = v0.w;
        dst[4] = v1.x; dst[5] = v1.y; dst[6] = v1.z; dst[7] = v1.w;
    }
    {
        const float4* g4 = (const float4*)W1;
        int i0 = tid * 2;
        float4 v0 = g4[i0], v1 = g4[i0 + 1];
        int f0 = tid * 8;
        int r = f0 >> 5, c = f0 & 31;
        float* dst = w1l + r * 36 + c;
        ((float4*)dst)[0] = v0; ((float4*)dst)[1] = v1;
    }
    {
        int f0 = tid * 4;
        int r = f0 >> 5, c = f0 & 31;
        *(float4*)(w2l + r * 36 + c) = ((const float4*)W2)[tid];
        *(float4*)(w3l + r * 36 + c) = ((const float4*)W3)[tid];
    }
    if (tid < 32) { bl[tid] = b1[tid]; bl[32 + tid] = b2[tid]; bl[64 + tid] = b3[tid]; }
    __syncthreads();

    const int r  = tid & 31;
    const int c0 = (tid >> 5) * 4;

    float4 a1 = *(const float4*)(bl + c0);
    #pragma unroll
    for (int k = 0; k < 64; ++k) {
        float xv = xs[r * 65 + k];
        float4 w = *(const float4*)(w1l + k * 36 + c0);
        a1.x = fmaf(xv, w.x, a1.x);
        a1.y = fmaf(xv, w.y, a1.y);
        a1.z = fmaf(xv, w.z, a1.z);
        a1.w = fmaf(xv, w.w, a1.w);
    }
    h1t[(c0 + 0) * 33 + r] = fmaxf(a1.x, 0.f);
    h1t[(c0 + 1) * 33 + r] = fmaxf(a1.y, 0.f);
    h1t[(c0 + 2) * 33 + r] = fmaxf(a1.z, 0.f);
    h1t[(c0 + 3) * 33 + r] = fmaxf(a1.w, 0.f);
    __syncthreads();

    float4 a2 = *(const float4*)(bl + 32 + c0);
    #pragma unroll
    for (int k = 0; k < 32; ++k) {
        float xv = h1t[k * 33 + r];
        float4 w = *(const float4*)(w2l + k * 36 + c0);
        a2.x = fmaf(xv, w.x, a2.x);
        a2.y = fmaf(xv, w.y, a2.y);
        a2.z = fmaf(xv, w.z, a2.z);
        a2.w = fmaf(xv, w.w, a2.w);
    }
    h2t[(c0 + 0) * 33 + r] = fmaxf(a2.x, 0.f);
    h2t[(c0 + 1) * 33 + r] = fmaxf(a2.y, 0.f);
    h2t[(c0 + 2) * 33 + r] = fmaxf(a2.z, 0.f);
    h2t[(c0 + 3) * 33 + r] = fmaxf(a2.w, 0.f);
    __syncthreads();

    float4 a3 = *(const float4*)(bl + 64 + c0);
    #pragma unroll
    for (int k = 0; k < 32; ++k) {
        float xv = h2t[k * 33 + r];
        float4 w = *(const float4*)(w3l + k * 36 + c0);
        a3.x = fmaf(xv, w.x, a3.x);
        a3.y = fmaf(xv, w.y, a3.y);
        a3.z = fmaf(xv, w.z, a3.z);
        a3.w = fmaf(xv, w.w, a3.w);
    }
    float v0 = fmaxf(a3.x, 0.f), v1 = fmaxf(a3.y, 0.f);
    float v2 = fmaxf(a3.z, 0.f), v3 = fmaxf(a3.w, 0.f);

    psums[(tid >> 5) * 32 + r] = v0 * v0 + v1 * v1 + v2 * v2 + v3 * v3;

    const float scale = isX ? LOG2E : 1.0f;
    union { _Float16 h[4]; uint2 u; } hh, ll;
    float sv0 = v0 * scale, sv1 = v1 * scale, sv2 = v2 * scale, sv3 = v3 * scale;
    hh.h[0] = (_Float16)sv0; hh.h[1] = (_Float16)sv1;
    hh.h[2] = (_Float16)sv2; hh.h[3] = (_Float16)sv3;
    ll.h[0] = (_Float16)(sv0 - (float)hh.h[0]);
    ll.h[1] = (_Float16)(sv1 - (float)hh.h[1]);
    ll.h[2] = (_Float16)(sv2 - (float)hh.h[2]);
    ll.h[3] = (_Float16)(sv3 - (float)hh.h[3]);
    {
        const int tile = blockIdx.x;
        const int ch = c0 >> 4, hb = (c0 >> 3) & 1, off = c0 & 7;
        const size_t fi = (((size_t)(tile * 2 + ch) * 64) + hb * 32 + r) * 8 + off;
        *(uint2*)(fh + fi) = hh.u;
        *(uint2*)(fl + fi) = ll.u;
    }

    __syncthreads();
    if (tid < 32) {
        float nrm = 0.f;
        #pragma unroll
        for (int g = 0; g < 8; ++g) nrm += psums[g * 32 + tid];
        ns[rowbase + tid] = NHALF_SC * nrm;   // exact f32 norm term
    }
}

// ---------------------------------------------------------------------------
// Kernel 2: fused pair kernel (R17: R16's DS-sharing, register-budgeted).
// R16 post-mortem: interleaved QK held accA+accB simultaneously -> ~160 regs
// -> (256,3) -> 3 blocks/CU vs grid needing 4 -> tail regression. R17:
// SERIALIZE the two QK phases (acc reused; phiA parked in 8 regs) so peak
// live ~115 < 128 -> (256,4) -> 4 blocks/CU, 16 waves/CU. K and Y fragments
// are still read from LDS ONCE per j-tile for both row-tiles (DS per
// 2 tile-computations: 16 KB -> 8 KB). QK-chain ILP loss is a non-factor
// (R13: neutral at this occupancy). Math bit-identical to R15/R16.
// ---------------------------------------------------------------------------
__global__ __launch_bounds__(256, 4) void pair_kernel(
    const _Float16* __restrict__ fh, const _Float16* __restrict__ fl,
    const _Float16* __restrict__ yfi, const float* __restrict__ ns,
    float* __restrict__ pout, float* __restrict__ psum)
{
    __shared__ char smem[2 * STAGEBUF];   // 33280 B

    const int tid  = threadIdx.x;
    const int wave = tid >> 6;
    const int lane = tid & 63;
    const int n    = lane & 31;
    const int h    = lane >> 5;

    const int rt0      = blockIdx.x * 8 + wave * 2;     // two Q 32-row tiles
    const int rowbase0 = rt0 * 32;
    const int rowbase1 = rowbase0 + 32;
    const int s        = blockIdx.y;
    const int ktile0   = (N_ROWS / 32) + s * NTILES;
    const int jstart   = s * JSLICE;

    // Q-side B fragments for both row-tiles (K=32: 2 chunks, hi/lo).
    const size_t qoffA = (size_t)rt0 * 1024 + (size_t)lane * 8;
    const size_t qoffB = qoffA + 1024;
    half8 qAh0 = ld_h8(fh + qoffA);
    half8 qAh1 = ld_h8(fh + qoffA + 512);
    half8 qAl0 = ld_h8(fl + qoffA);
    half8 qAl1 = ld_h8(fl + qoffA + 512);
    half8 qBh0 = ld_h8(fh + qoffB);
    half8 qBh1 = ld_h8(fh + qoffB + 512);
    half8 qBl0 = ld_h8(fl + qoffB);
    half8 qBl1 = ld_h8(fl + qoffB + 512);

    const float qvnA = ns[rowbase0 + n];
    const float qvnB = ns[rowbase1 + n];

    // Stage 2 tiles: 1024 16B chunks in 4 rounds + 64 ck floats (lane-indexed).
    auto prefetch = [&](int st, char* buf) {
        const int kt = ktile0 + 2 * st;
        const char* fhA = (const char*)(fh + (size_t)kt * 1024);
        const char* flA = (const char*)(fl + (size_t)kt * 1024);
        const char* fhB = (const char*)(fh + (size_t)(kt + 1) * 1024);
        const char* flB = (const char*)(fl + (size_t)(kt + 1) * 1024);
        const char* yA  = (const char*)(yfi + (size_t)(s * NTILES + 2 * st) * 2048);
        const char* yB  = (const char*)(yfi + (size_t)(s * NTILES + 2 * st + 1) * 2048);
        #pragma unroll
        for (int r = 0; r < 4; ++r) {
            const int c0 = wave * 64 + r * 256;   // wave-uniform
            const int c  = c0 + lane;
            const char* g; char* l;
            if (c0 < 128)      { g = fhA + (size_t)c * 16;         l = buf + c * 16; }
            else if (c0 < 256) { g = flA + (size_t)(c - 128) * 16; l = buf + 2048 + (c - 128) * 16; }
            else if (c0 < 384) { g = fhB + (size_t)(c - 256) * 16; l = buf + 4096 + (c - 256) * 16; }
            else if (c0 < 512) { g = flB + (size_t)(c - 384) * 16; l = buf + 6144 + (c - 384) * 16; }
            else if (c0 < 768) { g = yA  + (size_t)(c - 512) * 16; l = buf + YI_OFF + (c - 512) * 16; }
            else               { g = yB  + (size_t)(c - 768) * 16; l = buf + YI_OFF + 4096 + (c - 768) * 16; }
            __builtin_amdgcn_global_load_lds(
                (const __attribute__((address_space(1))) void*)g,
                (__attribute__((address_space(3))) void*)l, 16, 0, 0);
        }
        if (wave == 0) {
            // PER-LANE global address (R14 lesson).
            const char* gc = (const char*)(ns + N_ROWS + jstart + st * 64 + lane);
            __builtin_amdgcn_global_load_lds(
                (const __attribute__((address_space(1))) void*)gc,
                (__attribute__((address_space(3))) void*)(buf + CK_OFF), 4, 0, 0);
        }
    };

    f32x16 oA = {}, oB = {};   // O accumulators, one per row-tile

    auto compute = [&](const char* buf, int sub) {
        const char* kb  = buf + sub * 4096;
        const char* ckb = buf + CK_OFF + sub * 128;
        const char* yb  = buf + YI_OFF + sub * 4096;

        half8 kh0 = *(const half8*)(kb + lane * 16);
        half8 kh1 = *(const half8*)(kb + 1024 + lane * 16);
        half8 kl0 = *(const half8*)(kb + 2048 + lane * 16);
        half8 kl1 = *(const half8*)(kb + 3072 + lane * 16);

        // ---- tile A: QK (acc reused afterwards) + epilogue -> phiA ----
        half4v phiA[4], phiB[4];
        {
            f32x16 acc = {};
            acc = __builtin_amdgcn_mfma_f32_32x32x16_f16(kh0, qAh0, acc, 0, 0, 0);
            acc = __builtin_amdgcn_mfma_f32_32x32x16_f16(kh1, qAh1, acc, 0, 0, 0);
            acc = __builtin_amdgcn_mfma_f32_32x32x16_f16(kh0, qAl0, acc, 0, 0, 0);
            acc = __builtin_amdgcn_mfma_f32_32x32x16_f16(kh1, qAl1, acc, 0, 0, 0);
            acc = __builtin_amdgcn_mfma_f32_32x32x16_f16(kl0, qAh0, acc, 0, 0, 0);
            acc = __builtin_amdgcn_mfma_f32_32x32x16_f16(kl1, qAh1, acc, 0, 0, 0);
            #pragma unroll
            for (int g = 0; g < 4; ++g) {
                float4 ck4 = *(const float4*)(ckb + (8 * g + 4 * h) * 4);
                float w0 = __builtin_amdgcn_exp2f(fminf(acc[4*g+0] + (ck4.x + qvnA), 0.f));
                float w1 = __builtin_amdgcn_exp2f(fminf(acc[4*g+1] + (ck4.y + qvnA), 0.f));
                float w2 = __builtin_amdgcn_exp2f(fminf(acc[4*g+2] + (ck4.z + qvnA), 0.f));
                float w3 = __builtin_amdgcn_exp2f(fminf(acc[4*g+3] + (ck4.w + qvnA), 0.f));
                union { unsigned int u[2]; half4v v; } ph;
                ph.u[0] = __builtin_bit_cast(unsigned int, __builtin_amdgcn_cvt_pkrtz(w0, w1));
                ph.u[1] = __builtin_bit_cast(unsigned int, __builtin_amdgcn_cvt_pkrtz(w2, w3));
                phiA[g] = ph.v;
            }
        }
        // ---- tile B: QK + epilogue -> phiB ----
        {
            f32x16 acc = {};
            acc = __builtin_amdgcn_mfma_f32_32x32x16_f16(kh0, qBh0, acc, 0, 0, 0);
            acc = __builtin_amdgcn_mfma_f32_32x32x16_f16(kh1, qBh1, acc, 0, 0, 0);
            acc = __builtin_amdgcn_mfma_f32_32x32x16_f16(kh0, qBl0, acc, 0, 0, 0);
            acc = __builtin_amdgcn_mfma_f32_32x32x16_f16(kh1, qBl1, acc, 0, 0, 0);
            acc = __builtin_amdgcn_mfma_f32_32x32x16_f16(kl0, qBh0, acc, 0, 0, 0);
            acc = __builtin_amdgcn_mfma_f32_32x32x16_f16(kl1, qBh1, acc, 0, 0, 0);
            #pragma unroll
            for (int g = 0; g < 4; ++g) {
                float4 ck4 = *(const float4*)(ckb + (8 * g + 4 * h) * 4);
                float w0 = __builtin_amdgcn_exp2f(fminf(acc[4*g+0] + (ck4.x + qvnB), 0.f));
                float w1 = __builtin_amdgcn_exp2f(fminf(acc[4*g+1] + (ck4.y + qvnB), 0.f));
                float w2 = __builtin_amdgcn_exp2f(fminf(acc[4*g+2] + (ck4.z + qvnB), 0.f));
                float w3 = __builtin_amdgcn_exp2f(fminf(acc[4*g+3] + (ck4.w + qvnB), 0.f));
                union { unsigned int u[2]; half4v v; } ph;
                ph.u[0] = __builtin_bit_cast(unsigned int, __builtin_amdgcn_cvt_pkrtz(w0, w1));
                ph.u[1] = __builtin_bit_cast(unsigned int, __builtin_amdgcn_cvt_pkrtz(w2, w3));
                phiB[g] = ph.v;
            }
        }
        // ---- PV: one Y read per group feeds BOTH row-tiles ----
        #pragma unroll
        for (int g = 0; g < 4; ++g) {
            uint4 yv = *(const uint4*)(yb + (g * 64 + lane) * 16);
            union { unsigned int u[2]; half4v v; } yh, yl;
            yh.u[0] = yv.x; yh.u[1] = yv.y;
            yl.u[0] = yv.z; yl.u[1] = yv.w;
            oA = __builtin_amdgcn_mfma_f32_32x32x8f16(phiA[g], yh.v, oA, 0, 0, 0);
            oB = __builtin_amdgcn_mfma_f32_32x32x8f16(phiB[g], yh.v, oB, 0, 0, 0);
            oA = __builtin_amdgcn_mfma_f32_32x32x8f16(phiA[g], yl.v, oA, 0, 0, 0);
            oB = __builtin_amdgcn_mfma_f32_32x32x8f16(phiB[g], yl.v, oB, 0, 0, 0);
        }
    };

    prefetch(0, smem);
    __syncthreads();

    for (int st = 0; st < NSTAGES; ++st) {
        char* cur = smem + (st & 1) * STAGEBUF;
        if (st + 1 < NSTAGES) prefetch(st + 1, smem + ((st + 1) & 1) * STAGEBUF);
        compute(cur, 0);
        compute(cur, 1);
        __syncthreads();
    }

    // Writeout: col t = lane&31; rows i = (r&3)+8*(r>>2)+4h, both tiles.
    const int t = n;
    if (t <= 8) {
        #pragma unroll
        for (int r = 0; r < 16; ++r) {
            int i = (r & 3) + 8 * (r >> 2) + 4 * h;
            float vA = oA[r], vB = oB[r];
            if (t < 8) {
                pout[((size_t)s * N_ROWS + rowbase0 + i) * T_OUT + t] = vA;
                pout[((size_t)s * N_ROWS + rowbase1 + i) * T_OUT + t] = vB;
            } else {
                psum[(size_t)s * N_ROWS + rowbase0 + i] = vA;
                psum[(size_t)s * N_ROWS + rowbase1 + i] = vB;
            }
        }
    }
}

// ---------------------------------------------------------------------------
// Kernel 3: reduce partials across NSPLIT j-slices and normalize.
// ---------------------------------------------------------------------------
__global__ __launch_bounds__(256) void reduce_kernel(
    const float* __restrict__ pout, const float* __restrict__ psum,
    float* __restrict__ out)
{
    const int id = blockIdx.x * 256 + threadIdx.x;   // 0..65535
    const int i = id >> 3;
    float sv = 0.f, sw = 0.f;
    #pragma unroll
    for (int s = 0; s < NSPLIT; ++s) {
        sv += pout[(size_t)s * N_ROWS * T_OUT + id];
        sw += psum[(size_t)s * N_ROWS + i];
    }
    out[id] = sv / sw;
}

// ---------------------------------------------------------------------------
extern "C" void kernel_launch(void* const* d_in, const int* in_sizes, int n_in,
                              void* d_out, int out_size, void* d_ws, size_t ws_size,
                              hipStream_t stream)
{
    const float* X  = (const float*)d_in[0];
    const float* Y  = (const float*)d_in[1];
    const float* Yt = (const float*)d_in[2];
    const float* W1 = (const float*)d_in[3];
    const float* b1 = (const float*)d_in[4];
    const float* W2 = (const float*)d_in[5];
    const float* b2 = (const float*)d_in[6];
    const float* W3 = (const float*)d_in[7];
    const float* b3 = (const float*)d_in[8];
    float* out = (float*)d_out;

    char* ws = (char*)d_ws;
    const size_t n_feat = (size_t)((N_ROWS + M_ROWS) / 32) * 2 * 512;  // 524288 halves
    _Float16* fh  = (_Float16*)ws;   ws += n_feat * 2;                 // 1 MB
    _Float16* fl  = (_Float16*)ws;   ws += n_feat * 2;                 // 1 MB
    const size_t n_yfi = (size_t)(M_ROWS / JTILE) * 4 * 64 * 8;        // 524288 halves
    _Float16* yfi = (_Float16*)ws;   ws += n_yfi * 2;                  // 1 MB
    float*    ns  = (float*)ws;      ws += (N_ROWS + M_ROWS) * 4;      // 64 KB
    float*    pout = (float*)ws;     ws += (size_t)NSPLIT * N_ROWS * T_OUT * 4; // 8 MB
    float*    psum = (float*)ws;                                       // 1 MB

    // feat blocks (512) + ytt blocks (256) fused into one launch.
    prep_kernel<<<512 + 256, 256, 0, stream>>>(
        X, Y, Yt, W1, b1, W2, b2, W3, b3, fh, fl, yfi, ns);

    dim3 grid2(N_ROWS / 256, NSPLIT);
    pair_kernel<<<grid2, 256, 0, stream>>>(fh, fl, yfi, ns, pout, psum);

    reduce_kernel<<<(N_ROWS * T_OUT) / 256, 256, 0, stream>>>(pout, psum, out);
}

// Round 18
// 104.010 us; speedup vs baseline: 1.2100x; 1.2100x over previous
//
#include <hip/hip_runtime.h>
#include <hip/hip_bf16.h>
#include <cstddef>

#define N_ROWS 8192
#define M_ROWS 8192
#define D_IN   64
#define H_DIM  32
#define T_OUT  8

#define NSPLIT   16          // j-splits (blockIdx.y); 1024 blocks = 4/CU
#define JSLICE   (M_ROWS / NSPLIT)   // 512 cols per block
#define JTILE    32
#define NTILES   (JSLICE / JTILE)    // 16 j-tiles per block
#define NSTAGES  (NTILES / 2)        // 8 two-tile stages
#define LOG2E    1.4426950408889634f
#define NHALF_SC (-0.72134752044448169f)   // -0.5*log2(e)

// Stage buffer (2 j-tiles): KH_A 2048 | KL_A 2048 | KH_B 2048 | KL_B 2048 |
// YI_A 4096 | YI_B 4096 | CK 256  = 16640 B; double-buffered = 33280 B.
#define YI_OFF  8192
#define CK_OFF  16384
#define STAGEBUF 16640

typedef _Float16 half8  __attribute__((ext_vector_type(8)));
typedef _Float16 half4v __attribute__((ext_vector_type(4)));
typedef __fp16   fp16x2 __attribute__((ext_vector_type(2)));
typedef float    f32x16 __attribute__((ext_vector_type(16)));

__device__ __forceinline__ half8 ld_h8(const _Float16* p) {
    return *(const half8*)p;
}

// ---------------------------------------------------------------------------
// Feature storage: FRAGMENT-ORDER, K=32 (2 chunks of 16; norms applied in
// the pair epilogue as exact f32). For 32-row tile T, chunk c, lane
// l = h*32+n holds feat[T*32+n][16c+8h..+8) at ((T*2 + c)*64 + l)*8 halves.
// ---------------------------------------------------------------------------

// ---------------------------------------------------------------------------
// Kernel 1 (fused prep): blocks 0..511 = features (column-split MLP) + ns;
// blocks 512..767 = Y_target PV B-fragments (hi|lo interleaved).
// ---------------------------------------------------------------------------
__global__ __launch_bounds__(256) void prep_kernel(
    const float* __restrict__ X, const float* __restrict__ Y,
    const float* __restrict__ Yt,
    const float* __restrict__ W1, const float* __restrict__ b1,
    const float* __restrict__ W2, const float* __restrict__ b2,
    const float* __restrict__ W3, const float* __restrict__ b3,
    _Float16* __restrict__ fh, _Float16* __restrict__ fl,
    _Float16* __restrict__ yfi, float* __restrict__ ns)
{
    __shared__ float xs [32 * 65];
    __shared__ float w1l[64 * 36];
    __shared__ float w2l[32 * 36];
    __shared__ float w3l[32 * 36];
    __shared__ float h1t[32 * 33];
    __shared__ float h2t[32 * 33];
    __shared__ float psums[8 * 32];
    __shared__ float bl[96];

    const int tid = threadIdx.x;

    if (blockIdx.x >= 512) {
        // Ytt[j][t] = Yt[j][t] (t<8), 1 (t==8), 0 (t>8); hi|lo interleaved.
        const int idx = (blockIdx.x - 512) * 256 + tid;   // 0..65535
        const int lane = idx & 63;
        const int jtg  = idx >> 6;
        const int g    = jtg & 3;
        const int jt   = jtg >> 2;
        const int t    = lane & 31;
        const int h    = lane >> 5;
        const int j    = jt * 32 + g * 8 + h * 4;
        union { _Float16 hh[8]; uint4 u; } V;
        #pragma unroll
        for (int i = 0; i < 4; ++i) {
            float v = (t < T_OUT) ? Yt[(size_t)(j + i) * T_OUT + t]
                                  : (t == 8 ? 1.0f : 0.0f);
            _Float16 hi = (_Float16)v;     // RNE
            V.hh[i]     = hi;
            V.hh[4 + i] = (_Float16)(v - (float)hi);
        }
        *(uint4*)(yfi + (size_t)idx * 8) = V.u;
        return;
    }

    // ---- feat: rows 0..N-1 = MLP(X)*log2e; rows N.. = MLP(Y) unscaled. ----
    const int rowbase = blockIdx.x * 32;
    const bool isX = rowbase < N_ROWS;
    const float* src = isX ? (X + (size_t)rowbase * D_IN)
                           : (Y + (size_t)(rowbase - N_ROWS) * D_IN);

    {
        const float4* g4 = (const float4*)src;
        int i0 = tid * 2;
        float4 v0 = g4[i0], v1 = g4[i0 + 1];
        int f0 = tid * 8;
        int r = f0 >> 6, c = f0 & 63;
        float* dst = xs + r * 65 + c;
        dst[0] = v0.x; dst[1] = v0.y; dst[2] = v0.z; dst[3] = v0.w;
        dst[4] = v1.x; dst[5] = v1.y; dst[6] = v1.z; dst[7] = v1.w;
    }
    {
        const float4* g4 = (const float4*)W1;
        int i0 = tid * 2;
        float4 v0 = g4[i0], v1 = g4[i0 + 1];
        int f0 = tid * 8;
        int r = f0 >> 5, c = f0 & 31;
        float* dst = w1l + r * 36 + c;
        ((float4*)dst)[0] = v0; ((float4*)dst)[1] = v1;
    }
    {
        int f0 = tid * 4;
        int r = f0 >> 5, c = f0 & 31;
        *(float4*)(w2l + r * 36 + c) = ((const float4*)W2)[tid];
        *(float4*)(w3l + r * 36 + c) = ((const float4*)W3)[tid];
    }
    if (tid < 32) { bl[tid] = b1[tid]; bl[32 + tid] = b2[tid]; bl[64 + tid] = b3[tid]; }
    __syncthreads();

    const int r  = tid & 31;
    const int c0 = (tid >> 5) * 4;

    float4 a1 = *(const float4*)(bl + c0);
    #pragma unroll
    for (int k = 0; k < 64; ++k) {
        float xv = xs[r * 65 + k];
        float4 w = *(const float4*)(w1l + k * 36 + c0);
        a1.x = fmaf(xv, w.x, a1.x);
        a1.y = fmaf(xv, w.y, a1.y);
        a1.z = fmaf(xv, w.z, a1.z);
        a1.w = fmaf(xv, w.w, a1.w);
    }
    h1t[(c0 + 0) * 33 + r] = fmaxf(a1.x, 0.f);
    h1t[(c0 + 1) * 33 + r] = fmaxf(a1.y, 0.f);
    h1t[(c0 + 2) * 33 + r] = fmaxf(a1.z, 0.f);
    h1t[(c0 + 3) * 33 + r] = fmaxf(a1.w, 0.f);
    __syncthreads();

    float4 a2 = *(const float4*)(bl + 32 + c0);
    #pragma unroll
    for (int k = 0; k < 32; ++k) {
        float xv = h1t[k * 33 + r];
        float4 w = *(const float4*)(w2l + k * 36 + c0);
        a2.x = fmaf(xv, w.x, a2.x);
        a2.y = fmaf(xv, w.y, a2.y);
        a2.z = fmaf(xv, w.z, a2.z);
        a2.w = fmaf(xv, w.w, a2.w);
    }
    h2t[(c0 + 0) * 33 + r] = fmaxf(a2.x, 0.f);
    h2t[(c0 + 1) * 33 + r] = fmaxf(a2.y, 0.f);
    h2t[(c0 + 2) * 33 + r] = fmaxf(a2.z, 0.f);
    h2t[(c0 + 3) * 33 + r] = fmaxf(a2.w, 0.f);
    __syncthreads();

    float4 a3 = *(const float4*)(bl + 64 + c0);
    #pragma unroll
    for (int k = 0; k < 32; ++k) {
        float xv = h2t[k * 33 + r];
        float4 w = *(const float4*)(w3l + k * 36 + c0);
        a3.x = fmaf(xv, w.x, a3.x);
        a3.y = fmaf(xv, w.y, a3.y);
        a3.z = fmaf(xv, w.z, a3.z);
        a3.w = fmaf(xv, w.w, a3.w);
    }
    float v0 = fmaxf(a3.x, 0.f), v1 = fmaxf(a3.y, 0.f);
    float v2 = fmaxf(a3.z, 0.f), v3 = fmaxf(a3.w, 0.f);

    psums[(tid >> 5) * 32 + r] = v0 * v0 + v1 * v1 + v2 * v2 + v3 * v3;

    const float scale = isX ? LOG2E : 1.0f;
    union { _Float16 h[4]; uint2 u; } hh, ll;
    float sv0 = v0 * scale, sv1 = v1 * scale, sv2 = v2 * scale, sv3 = v3 * scale;
    hh.h[0] = (_Float16)sv0; hh.h[1] = (_Float16)sv1;
    hh.h[2] = (_Float16)sv2; hh.h[3] = (_Float16)sv3;
    ll.h[0] = (_Float16)(sv0 - (float)hh.h[0]);
    ll.h[1] = (_Float16)(sv1 - (float)hh.h[1]);
    ll.h[2] = (_Float16)(sv2 - (float)hh.h[2]);
    ll.h[3] = (_Float16)(sv3 - (float)hh.h[3]);
    {
        const int tile = blockIdx.x;
        const int ch = c0 >> 4, hb = (c0 >> 3) & 1, off = c0 & 7;
        const size_t fi = (((size_t)(tile * 2 + ch) * 64) + hb * 32 + r) * 8 + off;
        *(uint2*)(fh + fi) = hh.u;
        *(uint2*)(fl + fi) = ll.u;
    }

    __syncthreads();
    if (tid < 32) {
        float nrm = 0.f;
        #pragma unroll
        for (int g = 0; g < 8; ++g) nrm += psums[g * 32 + tid];
        ns[rowbase + tid] = NHALF_SC * nrm;   // exact f32 norm term
    }
}

// ---------------------------------------------------------------------------
// Kernel 2: fused pair kernel (R15 structure, reverted after R16/R17 both
// hit resource walls: R16 interleaved 2-row-tiles -> 160 regs -> (256,3)
// occupancy tail; R17 serialized variant at (256,4) -> spills, WRITE 56MB).
// Per tile: QK = 6x mfma_32x32x16 (K=32, 3-term hi/lo); norms in epilogue
// as exact f32 (qv per-lane reg, ck per-stage via lane-indexed
// global_load_lds). PV = 8x mfma_32x32x8 (hi+lo Y). Block-shared LDS
// staging, 2-tile stages, double-buffered. Verified 103.6 us total.
// ---------------------------------------------------------------------------
__global__ __launch_bounds__(256, 4) void pair_kernel(
    const _Float16* __restrict__ fh, const _Float16* __restrict__ fl,
    const _Float16* __restrict__ yfi, const float* __restrict__ ns,
    float* __restrict__ pout, float* __restrict__ psum)
{
    __shared__ char smem[2 * STAGEBUF];   // 33280 B

    const int tid  = threadIdx.x;
    const int wave = tid >> 6;
    const int lane = tid & 63;
    const int n    = lane & 31;
    const int h    = lane >> 5;

    const int rowtile = blockIdx.x * 4 + wave;          // Q 32-row tile
    const int rowbase = rowtile * 32;
    const int s       = blockIdx.y;
    const int ktile0  = (N_ROWS / 32) + s * NTILES;
    const int jstart  = s * JSLICE;

    // Q-side B fragments (K=32: 2 chunks, hi/lo), persist in regs.
    const size_t qoff = (size_t)rowtile * 1024 + (size_t)lane * 8;
    half8 qh0 = ld_h8(fh + qoff);
    half8 qh1 = ld_h8(fh + qoff + 512);
    half8 ql0 = ld_h8(fl + qoff);
    half8 ql1 = ld_h8(fl + qoff + 512);

    // Per-lane Q-row norm term (exact f32): row i = n.
    const float qvn = ns[rowbase + n];

    // Stage 2 tiles: 1024 16B chunks in 4 rounds + 64 ck floats (lane-indexed).
    auto prefetch = [&](int st, char* buf) {
        const int kt = ktile0 + 2 * st;
        const char* fhA = (const char*)(fh + (size_t)kt * 1024);
        const char* flA = (const char*)(fl + (size_t)kt * 1024);
        const char* fhB = (const char*)(fh + (size_t)(kt + 1) * 1024);
        const char* flB = (const char*)(fl + (size_t)(kt + 1) * 1024);
        const char* yA  = (const char*)(yfi + (size_t)(s * NTILES + 2 * st) * 2048);
        const char* yB  = (const char*)(yfi + (size_t)(s * NTILES + 2 * st + 1) * 2048);
        #pragma unroll
        for (int r = 0; r < 4; ++r) {
            const int c0 = wave * 64 + r * 256;   // wave-uniform
            const int c  = c0 + lane;
            const char* g; char* l;
            if (c0 < 128)      { g = fhA + (size_t)c * 16;         l = buf + c * 16; }
            else if (c0 < 256) { g = flA + (size_t)(c - 128) * 16; l = buf + 2048 + (c - 128) * 16; }
            else if (c0 < 384) { g = fhB + (size_t)(c - 256) * 16; l = buf + 4096 + (c - 256) * 16; }
            else if (c0 < 512) { g = flB + (size_t)(c - 384) * 16; l = buf + 6144 + (c - 384) * 16; }
            else if (c0 < 768) { g = yA  + (size_t)(c - 512) * 16; l = buf + YI_OFF + (c - 512) * 16; }
            else               { g = yB  + (size_t)(c - 768) * 16; l = buf + YI_OFF + 4096 + (c - 768) * 16; }
            __builtin_amdgcn_global_load_lds(
                (const __attribute__((address_space(1))) void*)g,
                (__attribute__((address_space(3))) void*)l, 16, 0, 0);
        }
        if (wave == 0) {
            // PER-LANE global address (R14 lesson).
            const char* gc = (const char*)(ns + N_ROWS + jstart + st * 64 + lane);
            __builtin_amdgcn_global_load_lds(
                (const __attribute__((address_space(1))) void*)gc,
                (__attribute__((address_space(3))) void*)(buf + CK_OFF), 4, 0, 0);
        }
    };

    f32x16 o = {};   // O accumulator: col t = lane&31, row i per reg

    auto compute = [&](const char* buf, int sub) {
        const char* kb = buf + sub * 4096;
        half8 kh0 = *(const half8*)(kb + lane * 16);
        half8 kh1 = *(const half8*)(kb + 1024 + lane * 16);
        half8 kl0 = *(const half8*)(kb + 2048 + lane * 16);
        half8 kl1 = *(const half8*)(kb + 3072 + lane * 16);

        // S^T = K·Q^T (log2e folded into X features): 6 MFMAs, K=32.
        f32x16 acc = {};
        acc = __builtin_amdgcn_mfma_f32_32x32x16_f16(kh0, qh0, acc, 0, 0, 0);
        acc = __builtin_amdgcn_mfma_f32_32x32x16_f16(kh1, qh1, acc, 0, 0, 0);
        acc = __builtin_amdgcn_mfma_f32_32x32x16_f16(kh0, ql0, acc, 0, 0, 0);
        acc = __builtin_amdgcn_mfma_f32_32x32x16_f16(kh1, ql1, acc, 0, 0, 0);
        acc = __builtin_amdgcn_mfma_f32_32x32x16_f16(kl0, qh0, acc, 0, 0, 0);
        acc = __builtin_amdgcn_mfma_f32_32x32x16_f16(kl1, qh1, acc, 0, 0, 0);

        // Epilogue: e = acc + qv(i) + ck(j) (exact f32); w = 2^min(e,0);
        // RTZ-pack hi into PV A-frags; PV vs hi+lo Y fragments.
        // C layout: reg r in group g -> j = 8g + 4h + (r&3).
        const char* ckb = buf + CK_OFF + sub * 128;
        const char* yb  = buf + YI_OFF + sub * 4096;
        #pragma unroll
        for (int g = 0; g < 4; ++g) {
            float4 ck4 = *(const float4*)(ckb + (8 * g + 4 * h) * 4);
            float w0 = __builtin_amdgcn_exp2f(fminf(acc[4*g+0] + (ck4.x + qvn), 0.f));
            float w1 = __builtin_amdgcn_exp2f(fminf(acc[4*g+1] + (ck4.y + qvn), 0.f));
            float w2 = __builtin_amdgcn_exp2f(fminf(acc[4*g+2] + (ck4.z + qvn), 0.f));
            float w3 = __builtin_amdgcn_exp2f(fminf(acc[4*g+3] + (ck4.w + qvn), 0.f));
            union { unsigned int u[2]; half4v v; } ph;
            ph.u[0] = __builtin_bit_cast(unsigned int, __builtin_amdgcn_cvt_pkrtz(w0, w1));
            ph.u[1] = __builtin_bit_cast(unsigned int, __builtin_amdgcn_cvt_pkrtz(w2, w3));
            uint4 yv = *(const uint4*)(yb + (g * 64 + lane) * 16);
            union { unsigned int u[2]; half4v v; } yh, yl;
            yh.u[0] = yv.x; yh.u[1] = yv.y;
            yl.u[0] = yv.z; yl.u[1] = yv.w;
            o = __builtin_amdgcn_mfma_f32_32x32x8f16(ph.v, yh.v, o, 0, 0, 0);
            o = __builtin_amdgcn_mfma_f32_32x32x8f16(ph.v, yl.v, o, 0, 0, 0);
        }
    };

    prefetch(0, smem);
    __syncthreads();

    for (int st = 0; st < NSTAGES; ++st) {
        char* cur = smem + (st & 1) * STAGEBUF;
        if (st + 1 < NSTAGES) prefetch(st + 1, smem + ((st + 1) & 1) * STAGEBUF);
        compute(cur, 0);
        compute(cur, 1);
        __syncthreads();
    }

    // Writeout: col t = lane&31; rows i = (r&3)+8*(r>>2)+4h.
    const int t = n;
    if (t <= 8) {
        #pragma unroll
        for (int r = 0; r < 16; ++r) {
            int i = (r & 3) + 8 * (r >> 2) + 4 * h;
            int row = rowbase + i;
            float v = o[r];
            if (t < 8)
                pout[((size_t)s * N_ROWS + row) * T_OUT + t] = v;
            else
                psum[(size_t)s * N_ROWS + row] = v;
        }
    }
}

// ---------------------------------------------------------------------------
// Kernel 3: reduce partials across NSPLIT j-slices and normalize.
// ---------------------------------------------------------------------------
__global__ __launch_bounds__(256) void reduce_kernel(
    const float* __restrict__ pout, const float* __restrict__ psum,
    float* __restrict__ out)
{
    const int id = blockIdx.x * 256 + threadIdx.x;   // 0..65535
    const int i = id >> 3;
    float sv = 0.f, sw = 0.f;
    #pragma unroll
    for (int s = 0; s < NSPLIT; ++s) {
        sv += pout[(size_t)s * N_ROWS * T_OUT + id];
        sw += psum[(size_t)s * N_ROWS + i];
    }
    out[id] = sv / sw;
}

// ---------------------------------------------------------------------------
extern "C" void kernel_launch(void* const* d_in, const int* in_sizes, int n_in,
                              void* d_out, int out_size, void* d_ws, size_t ws_size,
                              hipStream_t stream)
{
    const float* X  = (const float*)d_in[0];
    const float* Y  = (const float*)d_in[1];
    const float* Yt = (const float*)d_in[2];
    const float* W1 = (const float*)d_in[3];
    const float* b1 = (const float*)d_in[4];
    const float* W2 = (const float*)d_in[5];
    const float* b2 = (const float*)d_in[6];
    const float* W3 = (const float*)d_in[7];
    const float* b3 = (const float*)d_in[8];
    float* out = (float*)d_out;

    char* ws = (char*)d_ws;
    const size_t n_feat = (size_t)((N_ROWS + M_ROWS) / 32) * 2 * 512;  // 524288 halves
    _Float16* fh  = (_Float16*)ws;   ws += n_feat * 2;                 // 1 MB
    _Float16* fl  = (_Float16*)ws;   ws += n_feat * 2;                 // 1 MB
    const size_t n_yfi = (size_t)(M_ROWS / JTILE) * 4 * 64 * 8;        // 524288 halves
    _Float16* yfi = (_Float16*)ws;   ws += n_yfi * 2;                  // 1 MB
    float*    ns  = (float*)ws;      ws += (N_ROWS + M_ROWS) * 4;      // 64 KB
    float*    pout = (float*)ws;     ws += (size_t)NSPLIT * N_ROWS * T_OUT * 4; // 4 MB
    float*    psum = (float*)ws;                                       // 512 KB

    // feat blocks (512) + ytt blocks (256) fused into one launch.
    prep_kernel<<<512 + 256, 256, 0, stream>>>(
        X, Y, Yt, W1, b1, W2, b2, W3, b3, fh, fl, yfi, ns);

    dim3 grid2(N_ROWS / 128, NSPLIT);
    pair_kernel<<<grid2, 256, 0, stream>>>(fh, fl, yfi, ns, pout, psum);

    reduce_kernel<<<(N_ROWS * T_OUT) / 256, 256, 0, stream>>>(pout, psum, out);
}